// Round 4
// baseline (695.427 us; speedup 1.0000x reference)
//
#include <hip/hip_runtime.h>

// GraphAttentionLayer on MI355X (gfx950)
// N=8192, IN_F=128, N_HID=64, OUT_F=128
//
// R4 = R3 with native clang vector types (HIP_vector_type int4/uint4/float4
// are classes -> rejected by __builtin_nontemporal_load; use
// ext_vector_type instead).
//  - mask_kernel: adj (256MB int32 0/1) -> bitmask (8MB) coalesced stream.
//  - attn: barrier-free wave-independent flash attention; mask via 4
//    16B bitmask loads per tile (L2/L3-hit) instead of 32 scattered 4B
//    HBM loads.
//  - proj: b128 LDS reads.
//  - combine: split-K merge.

#define NN 8192
#define INF_ 128
#define NHID 64
#define OUTF 128
#define NEGC -9.0e15f

typedef unsigned short u16;
typedef __attribute__((ext_vector_type(8))) short bf16x8;
typedef __attribute__((ext_vector_type(4))) float f32x4;
typedef __attribute__((ext_vector_type(4))) int i32x4;
typedef __attribute__((ext_vector_type(4))) unsigned u32x4;

static __device__ __forceinline__ u16 f2bf(float x) {
  union { float f; unsigned u; } v; v.f = x;
  unsigned lsb = (v.u >> 16) & 1u;
  v.u += 0x7fffu + lsb;            // round-to-nearest-even
  return (u16)(v.u >> 16);
}
static __device__ __forceinline__ float bf2f(u16 h) {
  union { float f; unsigned u; } v; v.u = ((unsigned)h) << 16;
  return v.f;
}
static __device__ __forceinline__ f32x4 mfma16(bf16x8 a, bf16x8 b, f32x4 c) {
  return __builtin_amdgcn_mfma_f32_16x16x32_bf16(a, b, c, 0, 0, 0);
}

// ---------------------------------------------------------------- kernel 0
// adj[N][N] int32 -> bm[N][N/32] bitmask. One block per row; thread t packs
// cols t*32..t*32+31. Wave reads 8KB contiguous -> pure HBM stream.
__global__ __launch_bounds__(256) void mask_kernel(
    const int* __restrict__ adj, unsigned* __restrict__ bm) {
  const int r = blockIdx.x;
  const int t = threadIdx.x;
  const i32x4* src =
      reinterpret_cast<const i32x4*>(adj + (size_t)r * NN + t * 32);
  unsigned w = 0;
#pragma unroll
  for (int i = 0; i < 8; ++i) {
    i32x4 v = __builtin_nontemporal_load(src + i);
    w |= (v.x > 0 ? 1u : 0u) << (i * 4 + 0);
    w |= (v.y > 0 ? 1u : 0u) << (i * 4 + 1);
    w |= (v.z > 0 ? 1u : 0u) << (i * 4 + 2);
    w |= (v.w > 0 ? 1u : 0u) << (i * 4 + 3);
  }
  bm[r * (NN / 32) + t] = w;
}

// ---------------------------------------------------------------- kernel 1
__global__ __launch_bounds__(256) void proj_kernel(
    const float* __restrict__ h, const float* __restrict__ Ws,
    const float* __restrict__ Wt, const float* __restrict__ Wc,
    u16* __restrict__ whs_hi, u16* __restrict__ whs_lo,
    u16* __restrict__ wht_hi, u16* __restrict__ wht_lo,
    u16* __restrict__ whcT) {
  __shared__ f32x4 hbuf[8][32];   // 8 rows x 128 k, as float4
  const int tid = threadIdx.x;
  const int r0 = blockIdx.x * 8;
  hbuf[tid >> 5][tid & 31] =
      reinterpret_cast<const f32x4*>(h)[(size_t)r0 * 32 + tid];
  __syncthreads();

  float acc[8];
#pragma unroll
  for (int r = 0; r < 8; ++r) acc[r] = 0.f;

  if (tid < 128) {
    const float* W = (tid < 64) ? (Ws + tid) : (Wt + (tid - 64));
#pragma unroll 4
    for (int k4 = 0; k4 < 32; ++k4) {
      float w0 = W[(k4 * 4 + 0) * NHID];
      float w1 = W[(k4 * 4 + 1) * NHID];
      float w2 = W[(k4 * 4 + 2) * NHID];
      float w3 = W[(k4 * 4 + 3) * NHID];
#pragma unroll
      for (int r = 0; r < 8; ++r) {
        f32x4 hv = hbuf[r][k4];
        acc[r] += hv.x * w0 + hv.y * w1 + hv.z * w2 + hv.w * w3;
      }
    }
    const int col = tid & 63;
    u16* hi = (tid < 64) ? whs_hi : wht_hi;
    u16* lo = (tid < 64) ? whs_lo : wht_lo;
#pragma unroll
    for (int r = 0; r < 8; ++r) {
      float v = acc[r];
      u16 hb = f2bf(v);
      hi[(size_t)(r0 + r) * NHID + col] = hb;
      lo[(size_t)(r0 + r) * NHID + col] = f2bf(v - bf2f(hb));
    }
  } else {
    const int col = tid - 128;
    const float* W = Wc + col;
#pragma unroll 4
    for (int k4 = 0; k4 < 32; ++k4) {
      float w0 = W[(k4 * 4 + 0) * OUTF];
      float w1 = W[(k4 * 4 + 1) * OUTF];
      float w2 = W[(k4 * 4 + 2) * OUTF];
      float w3 = W[(k4 * 4 + 3) * OUTF];
#pragma unroll
      for (int r = 0; r < 8; ++r) {
        f32x4 hv = hbuf[r][k4];
        acc[r] += hv.x * w0 + hv.y * w1 + hv.z * w2 + hv.w * w3;
      }
    }
    union { u16 s[8]; u32x4 v; } pk;
#pragma unroll
    for (int r = 0; r < 8; ++r) pk.s[r] = f2bf(acc[r]);
    *reinterpret_cast<u32x4*>(whcT + (size_t)col * NN + r0) = pk.v;
  }
}

// ---------------------------------------------------------------- kernel 2
// Wave-independent flash attention; zero barriers. Wave gw = bIdx*4+w:
// rows rg*16..+15 (rg = gw & 511), column chunk = gw >> 9.
__global__ __launch_bounds__(256, 4) void attn_kernel(
    const u16* __restrict__ whs_hi, const u16* __restrict__ whs_lo,
    const u16* __restrict__ wht_hi, const u16* __restrict__ wht_lo,
    const u16* __restrict__ whcT, const unsigned* __restrict__ bm,
    float* __restrict__ Opart, float* __restrict__ mpart,
    float* __restrict__ lpart, float* __restrict__ out,
    int iters, int final_write) {
  // wave-private P slab, stride 136 u16: b128 reads land 2-way (free)
  __shared__ __align__(16) u16 Pbuf[4][16][136];

  const int tid = threadIdx.x;
  const int w = tid >> 6;
  const int lane = tid & 63;
  const int q = lane >> 4;
  const int ln = lane & 15;
  const int gw = blockIdx.x * 4 + w;
  const int rg = gw & 511;
  const int chunk = gw >> 9;
  const int row0 = rg * 16;

  // Loop-invariant A-fragments: Whs rows row0+ln, k = kh*32 + q*8 + j
  bf16x8 a_hi[2], a_lo[2];
#pragma unroll
  for (int kh = 0; kh < 2; ++kh) {
    a_hi[kh] = *reinterpret_cast<const bf16x8*>(
        whs_hi + (size_t)(row0 + ln) * NHID + kh * 32 + q * 8);
    a_lo[kh] = *reinterpret_cast<const bf16x8*>(
        whs_lo + (size_t)(row0 + ln) * NHID + kh * 32 + q * 8);
  }

  f32x4 oacc[8];
#pragma unroll
  for (int ot = 0; ot < 8; ++ot)
#pragma unroll
    for (int g = 0; g < 4; ++g) oacc[ot][g] = 0.f;

  float m_old[4], l_run[4];
#pragma unroll
  for (int g = 0; g < 4; ++g) { m_old[g] = -__builtin_inff(); l_run[g] = 0.f; }

  const u32x4* bm4 = reinterpret_cast<const u32x4*>(bm);  // [N][64]

  for (int jt = 0; jt < iters; ++jt) {
    const int j0 = (chunk * iters + jt) * 128;

    // bitmask for this wave's 4 rows x 128 cols: 4 uint4 loads (L2/L3-hit)
    u32x4 mk[4];
#pragma unroll
    for (int g = 0; g < 4; ++g)
      mk[g] = bm4[(size_t)(row0 + q * 4 + g) * 64 + (j0 >> 7)];

    // ---- scores S[16 x 128] (8 n-tiles), hi/lo split bf16 MFMA
    float s[8][4];
#pragma unroll
    for (int nt = 0; nt < 8; ++nt) {
      const int bcol = j0 + nt * 16 + ln;
      const u16* bh = wht_hi + (size_t)bcol * NHID + q * 8;
      const u16* bl = wht_lo + (size_t)bcol * NHID + q * 8;
      bf16x8 bh0 = *reinterpret_cast<const bf16x8*>(bh);
      bf16x8 bh1 = *reinterpret_cast<const bf16x8*>(bh + 32);
      bf16x8 bl0 = *reinterpret_cast<const bf16x8*>(bl);
      bf16x8 bl1 = *reinterpret_cast<const bf16x8*>(bl + 32);
      f32x4 sa;
#pragma unroll
      for (int g = 0; g < 4; ++g) sa[g] = 0.f;
      sa = mfma16(a_lo[0], bh0, sa);   // lo*hi
      sa = mfma16(a_hi[0], bl0, sa);   // hi*lo
      sa = mfma16(a_hi[0], bh0, sa);   // hi*hi
      sa = mfma16(a_lo[1], bh1, sa);
      sa = mfma16(a_hi[1], bl1, sa);
      sa = mfma16(a_hi[1], bh1, sa);
      const int bitpos = (nt & 1) * 16 + ln;
#pragma unroll
      for (int g = 0; g < 4; ++g) {
        unsigned wrd = (nt >> 1) == 0   ? mk[g].x
                       : (nt >> 1) == 1 ? mk[g].y
                       : (nt >> 1) == 2 ? mk[g].z
                                        : mk[g].w;
        s[nt][g] = ((wrd >> bitpos) & 1u) ? sa[g] : NEGC;
      }
    }

    // ---- in-wave online softmax (row r=q*4+g across 16 ln-lanes)
    float mr[4];
#pragma unroll
    for (int g = 0; g < 4; ++g) mr[g] = s[0][g];
#pragma unroll
    for (int nt = 1; nt < 8; ++nt)
#pragma unroll
      for (int g = 0; g < 4; ++g) mr[g] = fmaxf(mr[g], s[nt][g]);
#pragma unroll
    for (int msk = 1; msk <= 8; msk <<= 1)
#pragma unroll
      for (int g = 0; g < 4; ++g) mr[g] = fmaxf(mr[g], __shfl_xor(mr[g], msk));

    float mn[4], alpha[4], ps[4];
#pragma unroll
    for (int g = 0; g < 4; ++g) {
      mn[g] = fmaxf(m_old[g], mr[g]);
      alpha[g] = __expf(m_old[g] - mn[g]);  // -inf start -> 0
      m_old[g] = mn[g];
      ps[g] = 0.f;
    }
#pragma unroll
    for (int nt = 0; nt < 8; ++nt)
#pragma unroll
      for (int g = 0; g < 4; ++g) {
        float p = __expf(s[nt][g] - mn[g]);
        ps[g] += p;
        Pbuf[w][q * 4 + g][nt * 16 + ln] = f2bf(p);
      }
#pragma unroll
    for (int msk = 1; msk <= 8; msk <<= 1)
#pragma unroll
      for (int g = 0; g < 4; ++g) ps[g] += __shfl_xor(ps[g], msk);
#pragma unroll
    for (int g = 0; g < 4; ++g) l_run[g] = l_run[g] * alpha[g] + ps[g];
#pragma unroll
    for (int ot = 0; ot < 8; ++ot)
#pragma unroll
      for (int g = 0; g < 4; ++g) oacc[ot][g] *= alpha[g];

    // ---- PV: O[16x128] += P @ WhcT^T (wave-private LDS transpose)
#pragma unroll
    for (int kh = 0; kh < 4; ++kh) {
      bf16x8 pa = *reinterpret_cast<const bf16x8*>(
          &Pbuf[w][ln][kh * 32 + q * 8]);   // A: m=ln, k contiguous
#pragma unroll
      for (int ot = 0; ot < 8; ++ot) {
        bf16x8 wb = *reinterpret_cast<const bf16x8*>(
            whcT + (size_t)(ot * 16 + ln) * NN + j0 + kh * 32 + q * 8);
        oacc[ot] = mfma16(pa, wb, oacc[ot]);
      }
    }
  }

  // ---- epilogue
  if (final_write) {
#pragma unroll
    for (int ot = 0; ot < 8; ++ot)
#pragma unroll
      for (int g = 0; g < 4; ++g) {
        const int r = row0 + q * 4 + g;
        out[(size_t)r * OUTF + ot * 16 + ln] = oacc[ot][g] / l_run[g];
      }
  } else {
#pragma unroll
    for (int ot = 0; ot < 8; ++ot)
#pragma unroll
      for (int g = 0; g < 4; ++g) {
        const int r = row0 + q * 4 + g;
        Opart[((size_t)chunk * NN + r) * OUTF + ot * 16 + ln] = oacc[ot][g];
      }
    if (ln == 0) {
#pragma unroll
      for (int g = 0; g < 4; ++g) {
        const int r = row0 + q * 4 + g;
        mpart[chunk * NN + r] = m_old[g];
        lpart[chunk * NN + r] = l_run[g];
      }
    }
  }
}

// ---------------------------------------------------------------- kernel 3
__global__ __launch_bounds__(256) void combine_kernel(
    const float* __restrict__ Opart, const float* __restrict__ mpart,
    const float* __restrict__ lpart, float* __restrict__ out, int C) {
  const int idx = blockIdx.x * 256 + threadIdx.x;  // over N*OUTF
  const int row = idx >> 7;
  float M = -__builtin_inff();
  for (int c = 0; c < C; ++c) M = fmaxf(M, mpart[c * NN + row]);
  float den = 0.f, num = 0.f;
  for (int c = 0; c < C; ++c) {
    float wgt = __expf(mpart[c * NN + row] - M);
    den += lpart[c * NN + row] * wgt;
    num += Opart[(size_t)c * NN * OUTF + idx] * wgt;
  }
  out[idx] = num / den;
}

// ---------------------------------------------------------------- launch
extern "C" void kernel_launch(void* const* d_in, const int* in_sizes, int n_in,
                              void* d_out, int out_size, void* d_ws, size_t ws_size,
                              hipStream_t stream) {
  const float* h   = (const float*)d_in[0];
  const int*   adj = (const int*)d_in[1];
  const float* Ws  = (const float*)d_in[2];
  const float* Wt  = (const float*)d_in[3];
  const float* Wc  = (const float*)d_in[4];
  float* out = (float*)d_out;

  char* ws = (char*)d_ws;
  const size_t MB = 1024 * 1024;
  // ws: whs_hi|whs_lo|wht_hi|wht_lo (1MB each) | whcT (2MB) | bm (8MB)
  //     | mpart (256KB) | lpart (256KB) | Opart (C*4MB)
  u16* whs_hi = (u16*)(ws);
  u16* whs_lo = (u16*)(ws + 1 * MB);
  u16* wht_hi = (u16*)(ws + 2 * MB);
  u16* wht_lo = (u16*)(ws + 3 * MB);
  u16* whcT   = (u16*)(ws + 4 * MB);
  unsigned* bmask = (unsigned*)(ws + 6 * MB);
  float* mpart = (float*)(ws + 14 * MB);
  float* lpart = (float*)(ws + 14 * MB + 256 * 1024);
  float* Opart = (float*)(ws + 14 * MB + 512 * 1024);

  int C = 8;
  while (C > 1 &&
         14 * MB + 512 * 1024 + (size_t)C * NN * OUTF * sizeof(float) > ws_size)
    C >>= 1;
  const int final_write = (C == 1) ? 1 : 0;
  const int iters = 64 / C;

  mask_kernel<<<NN, 256, 0, stream>>>(adj, bmask);
  proj_kernel<<<NN / 8, 256, 0, stream>>>(h, Ws, Wt, Wc, whs_hi, whs_lo,
                                          wht_hi, wht_lo, whcT);
  attn_kernel<<<128 * C, 256, 0, stream>>>(whs_hi, whs_lo, wht_hi, wht_lo,
                                           whcT, bmask, Opart, mpart, lpart,
                                           out, iters, final_write);
  if (!final_write)
    combine_kernel<<<NN * OUTF / 256, 256, 0, stream>>>(Opart, mpart, lpart,
                                                        out, C);
}

// Round 5
// 578.612 us; speedup vs baseline: 1.2019x; 1.2019x over previous
//
#include <hip/hip_runtime.h>

// GraphAttentionLayer on MI355X (gfx950)
// N=8192, IN_F=128, N_HID=64, OUT_F=128
//
// R5: cooperative-staged flash attention (m97-style K-loop).
//  - Block = 512 thr (8 waves x 16 Q-rows = 128 rows). Grid = 64 x C.
//  - wht hi/lo staged to LDS double-buffered, one iter ahead (1 barrier/iter).
//    Padded col stride 72 u16 -> scores-B ds_read_b128 are 2-way (free).
//  - whcT B-frags register-prefetched from global (L2) during softmax.
//  - Pbuf wave-private padded (136 u16 stride), P: C-layout->A-layout.
//  - mask_kernel: adj -> 8MB bitmask (unchanged). proj/combine unchanged.

#define NN 8192
#define INF_ 128
#define NHID 64
#define OUTF 128
#define NEGC -9.0e15f

typedef unsigned short u16;
typedef __attribute__((ext_vector_type(8))) short bf16x8;
typedef __attribute__((ext_vector_type(4))) float f32x4;
typedef __attribute__((ext_vector_type(4))) int i32x4;
typedef __attribute__((ext_vector_type(4))) unsigned u32x4;

static __device__ __forceinline__ u16 f2bf(float x) {
  union { float f; unsigned u; } v; v.f = x;
  unsigned lsb = (v.u >> 16) & 1u;
  v.u += 0x7fffu + lsb;            // round-to-nearest-even
  return (u16)(v.u >> 16);
}
static __device__ __forceinline__ float bf2f(u16 h) {
  union { float f; unsigned u; } v; v.u = ((unsigned)h) << 16;
  return v.f;
}
static __device__ __forceinline__ f32x4 mfma16(bf16x8 a, bf16x8 b, f32x4 c) {
  return __builtin_amdgcn_mfma_f32_16x16x32_bf16(a, b, c, 0, 0, 0);
}

// ---------------------------------------------------------------- kernel 0
__global__ __launch_bounds__(256) void mask_kernel(
    const int* __restrict__ adj, unsigned* __restrict__ bm) {
  const int r = blockIdx.x;
  const int t = threadIdx.x;
  const i32x4* src =
      reinterpret_cast<const i32x4*>(adj + (size_t)r * NN + t * 32);
  unsigned w = 0;
#pragma unroll
  for (int i = 0; i < 8; ++i) {
    i32x4 v = __builtin_nontemporal_load(src + i);
    w |= (v.x > 0 ? 1u : 0u) << (i * 4 + 0);
    w |= (v.y > 0 ? 1u : 0u) << (i * 4 + 1);
    w |= (v.z > 0 ? 1u : 0u) << (i * 4 + 2);
    w |= (v.w > 0 ? 1u : 0u) << (i * 4 + 3);
  }
  bm[r * (NN / 32) + t] = w;
}

// ---------------------------------------------------------------- kernel 1
__global__ __launch_bounds__(256) void proj_kernel(
    const float* __restrict__ h, const float* __restrict__ Ws,
    const float* __restrict__ Wt, const float* __restrict__ Wc,
    u16* __restrict__ whs_hi, u16* __restrict__ whs_lo,
    u16* __restrict__ wht_hi, u16* __restrict__ wht_lo,
    u16* __restrict__ whcT) {
  __shared__ f32x4 hbuf[8][32];   // 8 rows x 128 k
  const int tid = threadIdx.x;
  const int r0 = blockIdx.x * 8;
  hbuf[tid >> 5][tid & 31] =
      reinterpret_cast<const f32x4*>(h)[(size_t)r0 * 32 + tid];
  __syncthreads();

  float acc[8];
#pragma unroll
  for (int r = 0; r < 8; ++r) acc[r] = 0.f;

  if (tid < 128) {
    const float* W = (tid < 64) ? (Ws + tid) : (Wt + (tid - 64));
#pragma unroll 4
    for (int k4 = 0; k4 < 32; ++k4) {
      float w0 = W[(k4 * 4 + 0) * NHID];
      float w1 = W[(k4 * 4 + 1) * NHID];
      float w2 = W[(k4 * 4 + 2) * NHID];
      float w3 = W[(k4 * 4 + 3) * NHID];
#pragma unroll
      for (int r = 0; r < 8; ++r) {
        f32x4 hv = hbuf[r][k4];
        acc[r] += hv.x * w0 + hv.y * w1 + hv.z * w2 + hv.w * w3;
      }
    }
    const int col = tid & 63;
    u16* hi = (tid < 64) ? whs_hi : wht_hi;
    u16* lo = (tid < 64) ? whs_lo : wht_lo;
#pragma unroll
    for (int r = 0; r < 8; ++r) {
      float v = acc[r];
      u16 hb = f2bf(v);
      hi[(size_t)(r0 + r) * NHID + col] = hb;
      lo[(size_t)(r0 + r) * NHID + col] = f2bf(v - bf2f(hb));
    }
  } else {
    const int col = tid - 128;
    const float* W = Wc + col;
#pragma unroll 4
    for (int k4 = 0; k4 < 32; ++k4) {
      float w0 = W[(k4 * 4 + 0) * OUTF];
      float w1 = W[(k4 * 4 + 1) * OUTF];
      float w2 = W[(k4 * 4 + 2) * OUTF];
      float w3 = W[(k4 * 4 + 3) * OUTF];
#pragma unroll
      for (int r = 0; r < 8; ++r) {
        f32x4 hv = hbuf[r][k4];
        acc[r] += hv.x * w0 + hv.y * w1 + hv.z * w2 + hv.w * w3;
      }
    }
    union { u16 s[8]; u32x4 v; } pk;
#pragma unroll
    for (int r = 0; r < 8; ++r) pk.s[r] = f2bf(acc[r]);
    *reinterpret_cast<u32x4*>(whcT + (size_t)col * NN + r0) = pk.v;
  }
}

// ---------------------------------------------------------------- kernel 2
// 8 waves x 16 rows = 128 rows/block. chunk = blockIdx & (C-1) (XCD-affine),
// rb = blockIdx >> cshift. wht staged to LDS double-buffered one iter ahead.
__global__ __launch_bounds__(512, 2) void attn_kernel(
    const u16* __restrict__ whs_hi, const u16* __restrict__ whs_lo,
    const u16* __restrict__ wht_hi, const u16* __restrict__ wht_lo,
    const u16* __restrict__ whcT, const unsigned* __restrict__ bm,
    float* __restrict__ Opart, float* __restrict__ mpart,
    float* __restrict__ lpart, float* __restrict__ out,
    int iters, int cshift, int final_write) {
  // staged wht: [buf][h][col*72 + k]  (col stride 72 u16 = 144B: b128 reads
  // at col*144 + kh*64 + q*16 -> bank start (4*ln)%32 -> 2-way, free)
  __shared__ __align__(16) u16 Bst[2][2][128 * 72];   // 72 KB
  // wave-private P: stride 136 u16 (272B) -> A-frag b128 reads 2-way free
  __shared__ __align__(16) u16 Pbuf[8][16][136];      // 34 KB

  const int tid = threadIdx.x;
  const int w = tid >> 6;
  const int lane = tid & 63;
  const int q = lane >> 4;
  const int ln = lane & 15;
  const int chunk = blockIdx.x & ((1 << cshift) - 1);
  const int rb = blockIdx.x >> cshift;
  const int row0 = rb * 128 + w * 16;

  // staging role: thread -> (col, hi/lo, half of 64 k-values)
  const int scol = tid >> 2;
  const int sh = (tid >> 1) & 1;
  const int shalf = tid & 1;
  const u16* sgbase = (sh ? wht_lo : wht_hi);
  u16* sdst0 = &Bst[0][sh][scol * 72 + shalf * 32];
  u16* sdst1 = &Bst[1][sh][scol * 72 + shalf * 32];

  // loop-invariant A-fragments (Whs rows row0+ln)
  bf16x8 a_hi[2], a_lo[2];
#pragma unroll
  for (int kh = 0; kh < 2; ++kh) {
    a_hi[kh] = *reinterpret_cast<const bf16x8*>(
        whs_hi + (size_t)(row0 + ln) * NHID + kh * 32 + q * 8);
    a_lo[kh] = *reinterpret_cast<const bf16x8*>(
        whs_lo + (size_t)(row0 + ln) * NHID + kh * 32 + q * 8);
  }

  f32x4 oacc[8];
#pragma unroll
  for (int ot = 0; ot < 8; ++ot)
#pragma unroll
    for (int g = 0; g < 4; ++g) oacc[ot][g] = 0.f;

  float m_old[4], l_run[4];
#pragma unroll
  for (int g = 0; g < 4; ++g) { m_old[g] = -__builtin_inff(); l_run[g] = 0.f; }

  const u32x4* bm4 = reinterpret_cast<const u32x4*>(bm);  // [N][64]
  const int jbase = chunk * iters;

  // ---- preload buf 0
  {
    const int j0 = jbase * 128;
    const u32x4* g4 = reinterpret_cast<const u32x4*>(
        sgbase + (size_t)(j0 + scol) * 64 + shalf * 32);
    u32x4 st0 = g4[0], st1 = g4[1], st2 = g4[2], st3 = g4[3];
    u32x4* d4 = reinterpret_cast<u32x4*>(sdst0);
    d4[0] = st0; d4[1] = st1; d4[2] = st2; d4[3] = st3;
  }
  __syncthreads();

  for (int jt = 0; jt < iters; ++jt) {
    const int buf = jt & 1;
    const int j0 = (jbase + jt) * 128;

    // ---- issue staging loads for jt+1 (land during this iter's compute)
    u32x4 st0, st1, st2, st3;
    if (jt + 1 < iters) {
      const u32x4* g4 = reinterpret_cast<const u32x4*>(
          sgbase + (size_t)((jbase + jt + 1) * 128 + scol) * 64 + shalf * 32);
      st0 = g4[0]; st1 = g4[1]; st2 = g4[2]; st3 = g4[3];
    }

    // ---- bitmask for this wave's 4 rows x 128 cols
    u32x4 mk[4];
#pragma unroll
    for (int g = 0; g < 4; ++g)
      mk[g] = bm4[(size_t)(row0 + q * 4 + g) * 64 + (jbase + jt)];

    // ---- scores S[16 x 128] from staged LDS B
    const u16* Bh = &Bst[buf][0][0];
    const u16* Bl = &Bst[buf][1][0];
    float s[8][4];
#pragma unroll
    for (int nt = 0; nt < 8; ++nt) {
      const int c72 = (nt * 16 + ln) * 72 + q * 8;
      bf16x8 bh0 = *reinterpret_cast<const bf16x8*>(&Bh[c72]);
      bf16x8 bh1 = *reinterpret_cast<const bf16x8*>(&Bh[c72 + 32]);
      bf16x8 bl0 = *reinterpret_cast<const bf16x8*>(&Bl[c72]);
      bf16x8 bl1 = *reinterpret_cast<const bf16x8*>(&Bl[c72 + 32]);
      f32x4 sa;
#pragma unroll
      for (int g = 0; g < 4; ++g) sa[g] = 0.f;
      sa = mfma16(a_lo[0], bh0, sa);
      sa = mfma16(a_hi[0], bl0, sa);
      sa = mfma16(a_hi[0], bh0, sa);
      sa = mfma16(a_lo[1], bh1, sa);
      sa = mfma16(a_hi[1], bl1, sa);
      sa = mfma16(a_hi[1], bh1, sa);
      const int bitpos = (nt & 1) * 16 + ln;
#pragma unroll
      for (int g = 0; g < 4; ++g) {
        unsigned wrd = (nt >> 1) == 0   ? mk[g].x
                       : (nt >> 1) == 1 ? mk[g].y
                       : (nt >> 1) == 2 ? mk[g].z
                                        : mk[g].w;
        s[nt][g] = ((wrd >> bitpos) & 1u) ? sa[g] : NEGC;
      }
    }

    // ---- prefetch whcT kh=0 B-frags (overlap softmax)
    bf16x8 wbA[8], wbB[8];
#pragma unroll
    for (int ot = 0; ot < 8; ++ot)
      wbA[ot] = *reinterpret_cast<const bf16x8*>(
          whcT + (size_t)(ot * 16 + ln) * NN + j0 + q * 8);

    // ---- in-wave online softmax
    float mr[4];
#pragma unroll
    for (int g = 0; g < 4; ++g) mr[g] = s[0][g];
#pragma unroll
    for (int nt = 1; nt < 8; ++nt)
#pragma unroll
      for (int g = 0; g < 4; ++g) mr[g] = fmaxf(mr[g], s[nt][g]);
#pragma unroll
    for (int msk = 1; msk <= 8; msk <<= 1)
#pragma unroll
      for (int g = 0; g < 4; ++g) mr[g] = fmaxf(mr[g], __shfl_xor(mr[g], msk));

    float mn[4], alpha[4], ps[4];
#pragma unroll
    for (int g = 0; g < 4; ++g) {
      mn[g] = fmaxf(m_old[g], mr[g]);
      alpha[g] = __expf(m_old[g] - mn[g]);
      m_old[g] = mn[g];
      ps[g] = 0.f;
    }
#pragma unroll
    for (int nt = 0; nt < 8; ++nt)
#pragma unroll
      for (int g = 0; g < 4; ++g) {
        float p = __expf(s[nt][g] - mn[g]);
        ps[g] += p;
        Pbuf[w][q * 4 + g][nt * 16 + ln] = f2bf(p);
      }
#pragma unroll
    for (int msk = 1; msk <= 8; msk <<= 1)
#pragma unroll
      for (int g = 0; g < 4; ++g) ps[g] += __shfl_xor(ps[g], msk);
#pragma unroll
    for (int g = 0; g < 4; ++g) l_run[g] = l_run[g] * alpha[g] + ps[g];
#pragma unroll
    for (int ot = 0; ot < 8; ++ot)
#pragma unroll
      for (int g = 0; g < 4; ++g) oacc[ot][g] *= alpha[g];

    // ---- PV with whcT double-register pipeline
#pragma unroll
    for (int kh = 0; kh < 4; ++kh) {
      bf16x8* cur = (kh & 1) ? wbB : wbA;
      bf16x8* nxt = (kh & 1) ? wbA : wbB;
      if (kh < 3) {
#pragma unroll
        for (int ot = 0; ot < 8; ++ot)
          nxt[ot] = *reinterpret_cast<const bf16x8*>(
              whcT + (size_t)(ot * 16 + ln) * NN + j0 + (kh + 1) * 32 + q * 8);
      }
      bf16x8 pa = *reinterpret_cast<const bf16x8*>(
          &Pbuf[w][ln][kh * 32 + q * 8]);
#pragma unroll
      for (int ot = 0; ot < 8; ++ot)
        oacc[ot] = mfma16(pa, cur[ot], oacc[ot]);
    }

    // ---- write staged regs to the other buffer, then block barrier
    if (jt + 1 < iters) {
      u32x4* d4 = reinterpret_cast<u32x4*>(buf ? sdst0 : sdst1);
      d4[0] = st0; d4[1] = st1; d4[2] = st2; d4[3] = st3;
    }
    __syncthreads();
  }

  // ---- epilogue
  if (final_write) {
#pragma unroll
    for (int ot = 0; ot < 8; ++ot)
#pragma unroll
      for (int g = 0; g < 4; ++g) {
        const int r = row0 + q * 4 + g;
        out[(size_t)r * OUTF + ot * 16 + ln] = oacc[ot][g] / l_run[g];
      }
  } else {
#pragma unroll
    for (int ot = 0; ot < 8; ++ot)
#pragma unroll
      for (int g = 0; g < 4; ++g) {
        const int r = row0 + q * 4 + g;
        Opart[((size_t)chunk * NN + r) * OUTF + ot * 16 + ln] = oacc[ot][g];
      }
    if (ln == 0) {
#pragma unroll
      for (int g = 0; g < 4; ++g) {
        const int r = row0 + q * 4 + g;
        mpart[chunk * NN + r] = m_old[g];
        lpart[chunk * NN + r] = l_run[g];
      }
    }
  }
}

// ---------------------------------------------------------------- kernel 3
__global__ __launch_bounds__(256) void combine_kernel(
    const float* __restrict__ Opart, const float* __restrict__ mpart,
    const float* __restrict__ lpart, float* __restrict__ out, int C) {
  const int idx = blockIdx.x * 256 + threadIdx.x;  // over N*OUTF
  const int row = idx >> 7;
  float M = -__builtin_inff();
  for (int c = 0; c < C; ++c) M = fmaxf(M, mpart[c * NN + row]);
  float den = 0.f, num = 0.f;
  for (int c = 0; c < C; ++c) {
    float wgt = __expf(mpart[c * NN + row] - M);
    den += lpart[c * NN + row] * wgt;
    num += Opart[(size_t)c * NN * OUTF + idx] * wgt;
  }
  out[idx] = num / den;
}

// ---------------------------------------------------------------- launch
extern "C" void kernel_launch(void* const* d_in, const int* in_sizes, int n_in,
                              void* d_out, int out_size, void* d_ws, size_t ws_size,
                              hipStream_t stream) {
  const float* h   = (const float*)d_in[0];
  const int*   adj = (const int*)d_in[1];
  const float* Ws  = (const float*)d_in[2];
  const float* Wt  = (const float*)d_in[3];
  const float* Wc  = (const float*)d_in[4];
  float* out = (float*)d_out;

  char* ws = (char*)d_ws;
  const size_t MB = 1024 * 1024;
  // ws: whs_hi|whs_lo|wht_hi|wht_lo (1MB each) | whcT (2MB) | bm (8MB)
  //     | mpart (256KB) | lpart (256KB) | Opart (C*4MB)
  u16* whs_hi = (u16*)(ws);
  u16* whs_lo = (u16*)(ws + 1 * MB);
  u16* wht_hi = (u16*)(ws + 2 * MB);
  u16* wht_lo = (u16*)(ws + 3 * MB);
  u16* whcT   = (u16*)(ws + 4 * MB);
  unsigned* bmask = (unsigned*)(ws + 6 * MB);
  float* mpart = (float*)(ws + 14 * MB);
  float* lpart = (float*)(ws + 14 * MB + 256 * 1024);
  float* Opart = (float*)(ws + 14 * MB + 512 * 1024);

  // C=4 (grid 256 = 1 block/CU) if ws allows, else C=1 direct-write
  int C = 4, cshift = 2;
  if (14 * MB + 512 * 1024 + (size_t)C * NN * OUTF * sizeof(float) > ws_size) {
    C = 1; cshift = 0;
  }
  const int final_write = (C == 1) ? 1 : 0;
  const int iters = 64 / C;

  mask_kernel<<<NN, 256, 0, stream>>>(adj, bmask);
  proj_kernel<<<NN / 8, 256, 0, stream>>>(h, Ws, Wt, Wc, whs_hi, whs_lo,
                                          wht_hi, wht_lo, whcT);
  attn_kernel<<<64 * C, 512, 0, stream>>>(whs_hi, whs_lo, wht_hi, wht_lo,
                                          whcT, bmask, Opart, mpart, lpart,
                                          out, iters, cshift, final_write);
  if (!final_write)
    combine_kernel<<<NN * OUTF / 256, 256, 0, stream>>>(Opart, mpart, lpart,
                                                        out, C);
}